// Round 1
// baseline (7239.275 us; speedup 1.0000x reference)
//
#include <hip/hip_runtime.h>

typedef __bf16 bf16;
typedef __attribute__((ext_vector_type(8))) __bf16 bf16x8;
typedef __attribute__((ext_vector_type(4))) __bf16 bf16x4;
typedef __attribute__((ext_vector_type(4))) float f32x4;

#define MFMA16(a,b,c) __builtin_amdgcn_mfma_f32_16x16x32_bf16((a),(b),(c),0,0,0)

// ---------------- elementwise / small kernels ----------------

__global__ __launch_bounds__(256) void cvt_kernel(const float* __restrict__ in,
                                                  bf16* __restrict__ out, int n4) {
    int stride = gridDim.x * 256;
    for (int i = blockIdx.x * 256 + threadIdx.x; i < n4; i += stride) {
        float4 v = ((const float4*)in)[i];
        bf16x4 o;
        o[0] = (bf16)v.x; o[1] = (bf16)v.y; o[2] = (bf16)v.z; o[3] = (bf16)v.w;
        ((bf16x4*)out)[i] = o;
    }
}

__global__ __launch_bounds__(256) void embed_kernel(const int* __restrict__ tok,
                                                    const float* __restrict__ ew,
                                                    float* __restrict__ X) {
    int m = blockIdx.x;
    int t = tok[m];
    ((float4*)(X + (size_t)m * 1024))[threadIdx.x] =
        ((const float4*)(ew + (size_t)t * 1024))[threadIdx.x];
}

template <bool FILM>
__global__ __launch_bounds__(256) void rmsnorm_kernel(const float* __restrict__ X,
                                                      const float* __restrict__ w,
                                                      const float* __restrict__ gamma,
                                                      const float* __restrict__ beta,
                                                      bf16* __restrict__ H) {
    int m = blockIdx.x, t = threadIdx.x;
    float4 xv = ((const float4*)(X + (size_t)m * 1024))[t];
    float ss = xv.x * xv.x + xv.y * xv.y + xv.z * xv.z + xv.w * xv.w;
#pragma unroll
    for (int off = 1; off < 64; off <<= 1) ss += __shfl_xor(ss, off);
    __shared__ float red[4];
    if ((t & 63) == 0) red[t >> 6] = ss;
    __syncthreads();
    float tot = red[0] + red[1] + red[2] + red[3];
    float sc = rsqrtf(tot * (1.0f / 1024.0f) + 1.1920929e-07f);
    float4 wv = ((const float4*)w)[t];
    float r0 = xv.x * sc * wv.x, r1 = xv.y * sc * wv.y;
    float r2 = xv.z * sc * wv.z, r3 = xv.w * sc * wv.w;
    if (FILM) {
        float4 gv = ((const float4*)gamma)[t];
        float4 bv = ((const float4*)beta)[t];
        r0 = r0 * gv.x + bv.x; r1 = r1 * gv.y + bv.y;
        r2 = r2 * gv.z + bv.z; r3 = r3 * gv.w + bv.w;
    }
    bf16x4 o;
    o[0] = (bf16)r0; o[1] = (bf16)r1; o[2] = (bf16)r2; o[3] = (bf16)r3;
    ((bf16x4*)(H + (size_t)m * 1024))[t] = o;
}

__global__ __launch_bounds__(256) void swiglu_kernel(const bf16* __restrict__ G,
                                                     const bf16* __restrict__ U,
                                                     bf16* __restrict__ FF) {
    size_t i = (size_t)blockIdx.x * 256 + threadIdx.x;
    bf16x8 gv = ((const bf16x8*)G)[i];
    bf16x8 uv = ((const bf16x8*)U)[i];
    bf16x8 o;
#pragma unroll
    for (int j = 0; j < 8; ++j) {
        float x = (float)gv[j], y = (float)uv[j];
        float s = x / (1.0f + __expf(-x));
        o[j] = (bf16)(s * y);
    }
    ((bf16x8*)FF)[i] = o;
}

// ---------------- GEMM: C[M,N] = A[M,K] @ B[N,K]^T (both row-major, bf16) ----------------
// MODE 0: Cb[idx] = bf16(acc)
// MODE 1: Xout = Xin + acc; D1 = acc            (o-proj residual, N==1024)
// MODE 2: Xout = Xin + s*(D1 + acc)             (fractal update,  N==1024)
// MODE 3: Cf[idx] = acc                          (lm_head, f32 out)

template <int MODE>
__global__ __launch_bounds__(256, 2) void gemm_bt(const bf16* __restrict__ A,
                                                  const bf16* __restrict__ B,
                                                  int M, int N, int K,
                                                  bf16* __restrict__ Cb, float* __restrict__ Cf,
                                                  const float* Xin, float* Xout,
                                                  float* D1, const float* sptr) {
    __shared__ __align__(16) bf16 As[128 * 72];
    __shared__ __align__(16) bf16 Bs[128 * 72];
    int bn = blockIdx.x, bm = blockIdx.y;
    int tid = threadIdx.x;
    int lane = tid & 63, wid = tid >> 6;
    int wr = wid >> 1, wc = wid & 1;
    int lr = lane & 15, lg = lane >> 4;
    const bf16* Ab = A + (size_t)bm * 128 * K;
    const bf16* Bb = B + (size_t)bn * 128 * K;

    f32x4 acc[4][4];
#pragma unroll
    for (int i = 0; i < 4; ++i)
#pragma unroll
        for (int j = 0; j < 4; ++j) acc[i][j] = (f32x4){0.f, 0.f, 0.f, 0.f};

    for (int kt = 0; kt < K; kt += 64) {
        __syncthreads();
#pragma unroll
        for (int i = 0; i < 4; ++i) {
            int cid = tid + 256 * i;
            int r = cid >> 3, c = (cid & 7) * 8;
            *(bf16x8*)(As + r * 72 + c) = *(const bf16x8*)(Ab + (size_t)r * K + kt + c);
            *(bf16x8*)(Bs + r * 72 + c) = *(const bf16x8*)(Bb + (size_t)r * K + kt + c);
        }
        __syncthreads();
#pragma unroll
        for (int kk = 0; kk < 64; kk += 32) {
            bf16x8 af[4], bfr[4];
#pragma unroll
            for (int mi = 0; mi < 4; ++mi)
                af[mi] = *(const bf16x8*)(As + (wr * 64 + mi * 16 + lr) * 72 + kk + lg * 8);
#pragma unroll
            for (int ni = 0; ni < 4; ++ni)
                bfr[ni] = *(const bf16x8*)(Bs + (wc * 64 + ni * 16 + lr) * 72 + kk + lg * 8);
#pragma unroll
            for (int mi = 0; mi < 4; ++mi)
#pragma unroll
                for (int ni = 0; ni < 4; ++ni)
                    acc[mi][ni] = MFMA16(af[mi], bfr[ni], acc[mi][ni]);
        }
    }

    float s = 1.0f;
    if (MODE == 2) s = sptr[0];
#pragma unroll
    for (int mi = 0; mi < 4; ++mi) {
#pragma unroll
        for (int ni = 0; ni < 4; ++ni) {
#pragma unroll
            for (int j = 0; j < 4; ++j) {
                int row = bm * 128 + wr * 64 + mi * 16 + lg * 4 + j;
                int col = bn * 128 + wc * 64 + ni * 16 + lr;
                size_t idx = (size_t)row * N + col;
                float v = acc[mi][ni][j];
                if (MODE == 0) Cb[idx] = (bf16)v;
                else if (MODE == 1) { Xout[idx] = Xin[idx] + v; D1[idx] = v; }
                else if (MODE == 2) { Xout[idx] = Xin[idx] + s * (D1[idx] + v); }
                else Cf[idx] = v;
            }
        }
    }
}

// ---------------- causal flash attention (all-transposed form) ----------------
// QKV: [2048][3072] bf16 (q|k|v each [*, H=16, hd=64]); AO: [2048][1024] bf16
// block = (q-tile of 64 rows) x (b,h); 4 waves, each owns 16 q rows.
// S^T = mfma(A=K, B=Q^T)  -> lane state per q = lane&15 (scalar m/l/alpha)
// O^T = mfma(A=V^T, B=P^T), V staged transposed in LDS, P^T via per-wave LDS.

__global__ __launch_bounds__(256) void attn_kernel(const bf16* __restrict__ QKV,
                                                   bf16* __restrict__ AO) {
    int qt = blockIdx.x, bh = blockIdx.y;
    int b = bh >> 4, h = bh & 15;
    int tid = threadIdx.x;
    int w = tid >> 6, lane = tid & 63;
    int lr = lane & 15, lg = lane >> 4;

    __shared__ __align__(16) bf16 Ks[64 * 72];
    __shared__ __align__(16) bf16 Vt[64 * 72];
    __shared__ __align__(16) bf16 Ps[4 * 16 * 72];
    bf16* Pw = Ps + w * 16 * 72;

    int qrow = b * 1024 + qt * 64 + w * 16 + lr;
    const bf16* qptr = QKV + (size_t)qrow * 3072 + h * 64;
    bf16x8 qf0 = *(const bf16x8*)(qptr + lg * 8);
    bf16x8 qf1 = *(const bf16x8*)(qptr + 32 + lg * 8);

    f32x4 o[4];
#pragma unroll
    for (int i = 0; i < 4; ++i) o[i] = (f32x4){0.f, 0.f, 0.f, 0.f};
    float m_run = -1e30f, l_run = 0.f;
    int gq = qt * 64 + w * 16 + lr;

    for (int kt = 0; kt <= qt; ++kt) {
        __syncthreads();
#pragma unroll
        for (int i = 0; i < 2; ++i) {
            int cid = tid + 256 * i;           // 512 chunks: 64 rows x 8
            int r = cid >> 3, c = cid & 7;
            const bf16* kvrow = QKV + (size_t)(b * 1024 + kt * 64 + r) * 3072 + h * 64;
            *(bf16x8*)(Ks + r * 72 + c * 8) = *(const bf16x8*)(kvrow + 1024 + c * 8);
            bf16x8 vv = *(const bf16x8*)(kvrow + 2048 + c * 8);
#pragma unroll
            for (int ii = 0; ii < 8; ++ii) Vt[(c * 8 + ii) * 72 + r] = vv[ii];
        }
        __syncthreads();

        f32x4 st[4];
#pragma unroll
        for (int i = 0; i < 4; ++i) st[i] = (f32x4){0.f, 0.f, 0.f, 0.f};
#pragma unroll
        for (int ki = 0; ki < 4; ++ki) {
            bf16x8 kf0 = *(const bf16x8*)(Ks + (ki * 16 + lr) * 72 + lg * 8);
            bf16x8 kf1 = *(const bf16x8*)(Ks + (ki * 16 + lr) * 72 + 32 + lg * 8);
            st[ki] = MFMA16(kf0, qf0, st[ki]);
            st[ki] = MFMA16(kf1, qf1, st[ki]);
        }
        bool diag = (kt == qt);
        float pm = -1e30f;
#pragma unroll
        for (int ki = 0; ki < 4; ++ki) {
#pragma unroll
            for (int j = 0; j < 4; ++j) {
                float sv = st[ki][j] * 0.125f;
                if (diag) {
                    int gk = kt * 64 + ki * 16 + lg * 4 + j;
                    if (gk > gq) sv = -1e30f;
                }
                st[ki][j] = sv;
                pm = fmaxf(pm, sv);
            }
        }
        pm = fmaxf(pm, __shfl_xor(pm, 16));
        pm = fmaxf(pm, __shfl_xor(pm, 32));
        float m_new = fmaxf(m_run, pm);
        float alpha = __expf(m_run - m_new);
        float rs = 0.f;
#pragma unroll
        for (int ki = 0; ki < 4; ++ki) {
#pragma unroll
            for (int j = 0; j < 4; ++j) {
                float pv = __expf(st[ki][j] - m_new);
                rs += pv;
                Pw[lr * 72 + ki * 16 + lg * 4 + j] = (bf16)pv;
            }
        }
        rs += __shfl_xor(rs, 16);
        rs += __shfl_xor(rs, 32);
        l_run = l_run * alpha + rs;
        m_run = m_new;
#pragma unroll
        for (int di = 0; di < 4; ++di) o[di] *= alpha;
#pragma unroll
        for (int dk = 0; dk < 2; ++dk) {
            bf16x8 pf = *(const bf16x8*)(Pw + lr * 72 + dk * 32 + lg * 8);
#pragma unroll
            for (int di = 0; di < 4; ++di) {
                bf16x8 vf = *(const bf16x8*)(Vt + (di * 16 + lr) * 72 + dk * 32 + lg * 8);
                o[di] = MFMA16(vf, pf, o[di]);
            }
        }
    }
    float inv = 1.0f / l_run;
    bf16* optr = AO + (size_t)qrow * 1024 + h * 64;
#pragma unroll
    for (int di = 0; di < 4; ++di)
#pragma unroll
        for (int j = 0; j < 4; ++j)
            optr[di * 16 + lg * 4 + j] = (bf16)(o[di][j] * inv);
}

// ---------------- driver ----------------

extern "C" void kernel_launch(void* const* d_in, const int* in_sizes, int n_in,
                              void* d_out, int out_size, void* d_ws, size_t ws_size,
                              hipStream_t stream) {
    const int* tokens = (const int*)d_in[0];
    const float* embed_w = (const float*)d_in[1];
    const float* qkv_w = (const float*)d_in[2];
    const float* o_w = (const float*)d_in[3];
    const float* gate_w = (const float*)d_in[4];
    const float* up_w = (const float*)d_in[5];
    const float* down_w = (const float*)d_in[6];
    const float* norm1_w = (const float*)d_in[7];
    const float* norm2_w = (const float*)d_in[8];
    const float* scale_gamma = (const float*)d_in[9];
    const float* scale_beta = (const float*)d_in[10];
    const float* iter_scale = (const float*)d_in[11];
    const float* norm_w = (const float*)d_in[12];
    const float* lm_head_w = (const float*)d_in[13];

    char* p = (char*)d_ws;
    auto alloc = [&](size_t nbytes) -> char* {
        char* r = p;
        p += (nbytes + 255) & ~(size_t)255;
        return r;
    };
    bf16* WQKV = (bf16*)alloc(3072ull * 1024 * 2);
    bf16* WO   = (bf16*)alloc(1024ull * 1024 * 2);
    bf16* WG   = (bf16*)alloc(2048ull * 1024 * 2);
    bf16* WU   = (bf16*)alloc(2048ull * 1024 * 2);
    bf16* WD   = (bf16*)alloc(1024ull * 2048 * 2);
    bf16* WLM  = (bf16*)alloc(32000ull * 1024 * 2);
    float* X   = (float*)alloc(2048ull * 1024 * 4);
    float* X1  = (float*)alloc(2048ull * 1024 * 4);
    float* D1  = (float*)alloc(2048ull * 1024 * 4);
    bf16* H    = (bf16*)alloc(2048ull * 1024 * 2);
    bf16* QKVb = (bf16*)alloc(2048ull * 3072 * 2);
    bf16* AO   = (bf16*)alloc(2048ull * 1024 * 2);
    bf16* G    = (bf16*)alloc(2048ull * 2048 * 2);
    bf16* U    = (bf16*)alloc(2048ull * 2048 * 2);
    bf16* FF   = (bf16*)alloc(2048ull * 2048 * 2);

    cvt_kernel<<<1024, 256, 0, stream>>>(qkv_w, WQKV, 3072 * 1024 / 4);
    cvt_kernel<<<1024, 256, 0, stream>>>(o_w, WO, 1024 * 1024 / 4);
    cvt_kernel<<<1024, 256, 0, stream>>>(gate_w, WG, 2048 * 1024 / 4);
    cvt_kernel<<<1024, 256, 0, stream>>>(up_w, WU, 2048 * 1024 / 4);
    cvt_kernel<<<1024, 256, 0, stream>>>(down_w, WD, 1024 * 2048 / 4);
    cvt_kernel<<<2048, 256, 0, stream>>>(lm_head_w, WLM, 32000 * 1024 / 4);
    embed_kernel<<<2048, 256, 0, stream>>>(tokens, embed_w, X);

    for (int l = 0; l < 32; ++l) {
        const float* gm = scale_gamma + (size_t)(l >> 3) * 1024;
        const float* bt = scale_beta + (size_t)(l >> 3) * 1024;
        rmsnorm_kernel<true><<<2048, 256, 0, stream>>>(X, norm1_w, gm, bt, H);
        gemm_bt<0><<<dim3(24, 16), 256, 0, stream>>>(H, WQKV, 2048, 3072, 1024,
                                                     QKVb, nullptr, nullptr, nullptr, nullptr, nullptr);
        attn_kernel<<<dim3(16, 32), 256, 0, stream>>>(QKVb, AO);
        gemm_bt<1><<<dim3(8, 16), 256, 0, stream>>>(AO, WO, 2048, 1024, 1024,
                                                    nullptr, nullptr, X, X1, D1, nullptr);
        rmsnorm_kernel<true><<<2048, 256, 0, stream>>>(X1, norm2_w, gm, bt, H);
        gemm_bt<0><<<dim3(16, 16), 256, 0, stream>>>(H, WG, 2048, 2048, 1024,
                                                     G, nullptr, nullptr, nullptr, nullptr, nullptr);
        gemm_bt<0><<<dim3(16, 16), 256, 0, stream>>>(H, WU, 2048, 2048, 1024,
                                                     U, nullptr, nullptr, nullptr, nullptr, nullptr);
        swiglu_kernel<<<2048, 256, 0, stream>>>(G, U, FF);
        gemm_bt<2><<<dim3(8, 16), 256, 0, stream>>>(FF, WD, 2048, 1024, 2048,
                                                    nullptr, nullptr, X, X, D1, iter_scale + l);
    }
    rmsnorm_kernel<false><<<2048, 256, 0, stream>>>(X, norm_w, nullptr, nullptr, H);
    gemm_bt<3><<<dim3(250, 16), 256, 0, stream>>>(H, WLM, 2048, 32000, 1024,
                                                  nullptr, (float*)d_out, nullptr, nullptr, nullptr, nullptr);
}

// Round 3
// 5423.729 us; speedup vs baseline: 1.3347x; 1.3347x over previous
//
#include <hip/hip_runtime.h>

typedef __bf16 bf16;
typedef __attribute__((ext_vector_type(8))) __bf16 bf16x8;
typedef __attribute__((ext_vector_type(4))) __bf16 bf16x4;
typedef __attribute__((ext_vector_type(4))) float f32x4;

#define MFMA16(a,b,c) __builtin_amdgcn_mfma_f32_16x16x32_bf16((a),(b),(c),0,0,0)

__device__ __forceinline__ void gload16(const void* g, void* l) {
    __builtin_amdgcn_global_load_lds((const __attribute__((address_space(1))) void*)g,
                                     (__attribute__((address_space(3))) void*)l, 16, 0, 0);
}

// ---------------- elementwise / small kernels ----------------

__global__ __launch_bounds__(256) void cvt_kernel(const float* __restrict__ in,
                                                  bf16* __restrict__ out, int n4) {
    int stride = gridDim.x * 256;
    for (int i = blockIdx.x * 256 + threadIdx.x; i < n4; i += stride) {
        float4 v = ((const float4*)in)[i];
        bf16x4 o;
        o[0] = (bf16)v.x; o[1] = (bf16)v.y; o[2] = (bf16)v.z; o[3] = (bf16)v.w;
        ((bf16x4*)out)[i] = o;
    }
}

__global__ __launch_bounds__(256) void embed_kernel(const int* __restrict__ tok,
                                                    const float* __restrict__ ew,
                                                    float* __restrict__ X) {
    int m = blockIdx.x;
    int t = tok[m];
    ((float4*)(X + (size_t)m * 1024))[threadIdx.x] =
        ((const float4*)(ew + (size_t)t * 1024))[threadIdx.x];
}

template <bool FILM>
__global__ __launch_bounds__(256) void rmsnorm_kernel(const float* __restrict__ X,
                                                      const float* __restrict__ w,
                                                      const float* __restrict__ gamma,
                                                      const float* __restrict__ beta,
                                                      bf16* __restrict__ H) {
    int m = blockIdx.x, t = threadIdx.x;
    float4 xv = ((const float4*)(X + (size_t)m * 1024))[t];
    float ss = xv.x * xv.x + xv.y * xv.y + xv.z * xv.z + xv.w * xv.w;
#pragma unroll
    for (int off = 1; off < 64; off <<= 1) ss += __shfl_xor(ss, off);
    __shared__ float red[4];
    if ((t & 63) == 0) red[t >> 6] = ss;
    __syncthreads();
    float tot = red[0] + red[1] + red[2] + red[3];
    float sc = rsqrtf(tot * (1.0f / 1024.0f) + 1.1920929e-07f);
    float4 wv = ((const float4*)w)[t];
    float r0 = xv.x * sc * wv.x, r1 = xv.y * sc * wv.y;
    float r2 = xv.z * sc * wv.z, r3 = xv.w * sc * wv.w;
    if (FILM) {
        float4 gv = ((const float4*)gamma)[t];
        float4 bv = ((const float4*)beta)[t];
        r0 = r0 * gv.x + bv.x; r1 = r1 * gv.y + bv.y;
        r2 = r2 * gv.z + bv.z; r3 = r3 * gv.w + bv.w;
    }
    bf16x4 o;
    o[0] = (bf16)r0; o[1] = (bf16)r1; o[2] = (bf16)r2; o[3] = (bf16)r3;
    ((bf16x4*)(H + (size_t)m * 1024))[t] = o;
}

// ---------------- GEMM: C[M,N] = A[M,K] @ B[N,K]^T, global_load_lds staging ----------------
// MT: row-fragments per wave (BM = 32*MT). Tile = BM x 128, BK=64, 4 waves (2x2).
// MODE 0: Cb = bf16(acc)
// MODE 1: Xout = Xin + acc                       (o-proj residual)
// MODE 2: Xout = Xin + s*((Xin2-Xin) + acc)      (fractal update)
// MODE 3: Cf = acc                               (lm_head, f32 out)

template <int MT, int MODE>
__global__ __launch_bounds__(256, 2) void gemm_bt(const bf16* __restrict__ A,
                                                  const bf16* __restrict__ B,
                                                  int N, int K,
                                                  bf16* __restrict__ Cb, float* __restrict__ Cf,
                                                  const float* __restrict__ Xin,
                                                  const float* __restrict__ Xin2,
                                                  float* __restrict__ Xout,
                                                  const float* __restrict__ sptr) {
    constexpr int BM = 32 * MT;
    __shared__ __align__(16) bf16 As[BM * 64];
    __shared__ __align__(16) bf16 Bs[128 * 64];
    const int bn = blockIdx.x, bm = blockIdx.y;
    const int tid = threadIdx.x, lane = tid & 63, w = tid >> 6;
    const int wr = w >> 1, wc = w & 1, lr = lane & 15, lg = lane >> 4;
    const bf16* Ab = A + (size_t)bm * BM * K;
    const bf16* Bb = B + (size_t)bn * 128 * K;

    f32x4 acc[MT][4];
#pragma unroll
    for (int i = 0; i < MT; ++i)
#pragma unroll
        for (int j = 0; j < 4; ++j) acc[i][j] = (f32x4){0.f, 0.f, 0.f, 0.f};

    for (int kt = 0; kt < K; kt += 64) {
        __syncthreads();
#pragma unroll
        for (int i = 0; i < MT; ++i) {
            int cw = i * 256 + w * 64;
            int cid = cw + lane;
            gload16(Ab + (size_t)(cid >> 3) * K + kt + (cid & 7) * 8, As + cw * 8);
        }
#pragma unroll
        for (int i = 0; i < 4; ++i) {
            int cw = i * 256 + w * 64;
            int cid = cw + lane;
            gload16(Bb + (size_t)(cid >> 3) * K + kt + (cid & 7) * 8, Bs + cw * 8);
        }
        __syncthreads();
#pragma unroll
        for (int kk = 0; kk < 64; kk += 32) {
            bf16x8 af[MT], bfr[4];
#pragma unroll
            for (int mi = 0; mi < MT; ++mi)
                af[mi] = *(const bf16x8*)(As + (wr * (16 * MT) + mi * 16 + lr) * 64 + kk + lg * 8);
#pragma unroll
            for (int ni = 0; ni < 4; ++ni)
                bfr[ni] = *(const bf16x8*)(Bs + (wc * 64 + ni * 16 + lr) * 64 + kk + lg * 8);
#pragma unroll
            for (int mi = 0; mi < MT; ++mi)
#pragma unroll
                for (int ni = 0; ni < 4; ++ni)
                    acc[mi][ni] = MFMA16(af[mi], bfr[ni], acc[mi][ni]);
        }
    }

    float s1 = (MODE == 2) ? sptr[0] : 0.f;
#pragma unroll
    for (int mi = 0; mi < MT; ++mi) {
#pragma unroll
        for (int ni = 0; ni < 4; ++ni) {
#pragma unroll
            for (int j = 0; j < 4; ++j) {
                int row = bm * BM + wr * (16 * MT) + mi * 16 + lg * 4 + j;
                int col = bn * 128 + wc * 64 + ni * 16 + lr;
                size_t idx = (size_t)row * N + col;
                float v = acc[mi][ni][j];
                if (MODE == 0) Cb[idx] = (bf16)v;
                else if (MODE == 1) Xout[idx] = Xin[idx] + v;
                else if (MODE == 2) Xout[idx] = Xin[idx] + s1 * (Xin2[idx] - Xin[idx] + v);
                else Cf[idx] = v;
            }
        }
    }
}

// ---------------- fused gate+up GEMM with SwiGLU epilogue ----------------
// FF[2048,2048] = silu(H @ Wg^T) * (H @ Wu^T), K=1024. Tile 128x128, dual acc.

__global__ __launch_bounds__(256, 2) void gemm_gateup(const bf16* __restrict__ A,
                                                      const bf16* __restrict__ Bg,
                                                      const bf16* __restrict__ Bu,
                                                      bf16* __restrict__ FF) {
    const int K = 1024, N = 2048;
    __shared__ __align__(16) bf16 As[128 * 64];
    __shared__ __align__(16) bf16 Gs[128 * 64];
    __shared__ __align__(16) bf16 Us[128 * 64];
    const int bn = blockIdx.x, bm = blockIdx.y;
    const int tid = threadIdx.x, lane = tid & 63, w = tid >> 6;
    const int wr = w >> 1, wc = w & 1, lr = lane & 15, lg = lane >> 4;
    const bf16* Ab = A + (size_t)bm * 128 * K;
    const bf16* Gb = Bg + (size_t)bn * 128 * K;
    const bf16* Ub = Bu + (size_t)bn * 128 * K;

    f32x4 ag[4][4], au[4][4];
#pragma unroll
    for (int i = 0; i < 4; ++i)
#pragma unroll
        for (int j = 0; j < 4; ++j) {
            ag[i][j] = (f32x4){0.f, 0.f, 0.f, 0.f};
            au[i][j] = (f32x4){0.f, 0.f, 0.f, 0.f};
        }

    for (int kt = 0; kt < K; kt += 64) {
        __syncthreads();
#pragma unroll
        for (int i = 0; i < 4; ++i) {
            int cw = i * 256 + w * 64;
            int cid = cw + lane;
            size_t ro = (size_t)(cid >> 3) * K + kt + (cid & 7) * 8;
            gload16(Ab + ro, As + cw * 8);
            gload16(Gb + ro, Gs + cw * 8);
            gload16(Ub + ro, Us + cw * 8);
        }
        __syncthreads();
#pragma unroll
        for (int kk = 0; kk < 64; kk += 32) {
            bf16x8 af[4], gf[4], uf[4];
#pragma unroll
            for (int mi = 0; mi < 4; ++mi)
                af[mi] = *(const bf16x8*)(As + (wr * 64 + mi * 16 + lr) * 64 + kk + lg * 8);
#pragma unroll
            for (int ni = 0; ni < 4; ++ni) {
                gf[ni] = *(const bf16x8*)(Gs + (wc * 64 + ni * 16 + lr) * 64 + kk + lg * 8);
                uf[ni] = *(const bf16x8*)(Us + (wc * 64 + ni * 16 + lr) * 64 + kk + lg * 8);
            }
#pragma unroll
            for (int mi = 0; mi < 4; ++mi)
#pragma unroll
                for (int ni = 0; ni < 4; ++ni) {
                    ag[mi][ni] = MFMA16(af[mi], gf[ni], ag[mi][ni]);
                    au[mi][ni] = MFMA16(af[mi], uf[ni], au[mi][ni]);
                }
        }
    }

#pragma unroll
    for (int mi = 0; mi < 4; ++mi) {
#pragma unroll
        for (int ni = 0; ni < 4; ++ni) {
#pragma unroll
            for (int j = 0; j < 4; ++j) {
                int row = bm * 128 + wr * 64 + mi * 16 + lg * 4 + j;
                int col = bn * 128 + wc * 64 + ni * 16 + lr;
                float g = ag[mi][ni][j], u = au[mi][ni][j];
                float sg = g / (1.0f + __expf(-g));
                FF[(size_t)row * N + col] = (bf16)(sg * u);
            }
        }
    }
}

// ---------------- causal flash attention (all-transposed form, round-1 verified) ----------------

__global__ __launch_bounds__(256) void attn_kernel(const bf16* __restrict__ QKV,
                                                   bf16* __restrict__ AO) {
    const int qt = blockIdx.x, bh = blockIdx.y;
    const int b = bh >> 4, h = bh & 15;
    const int tid = threadIdx.x;
    const int w = tid >> 6, lane = tid & 63;
    const int lr = lane & 15, lg = lane >> 4;

    __shared__ __align__(16) bf16 Ks[64 * 72];
    __shared__ __align__(16) bf16 Vt[64 * 72];
    __shared__ __align__(16) bf16 Ps[4 * 16 * 72];
    bf16* Pw = Ps + w * 16 * 72;

    const int qrow = b * 1024 + qt * 64 + w * 16 + lr;
    const bf16* qptr = QKV + (size_t)qrow * 3072 + h * 64;
    bf16x8 qf0 = *(const bf16x8*)(qptr + lg * 8);
    bf16x8 qf1 = *(const bf16x8*)(qptr + 32 + lg * 8);

    f32x4 o[4];
#pragma unroll
    for (int i = 0; i < 4; ++i) o[i] = (f32x4){0.f, 0.f, 0.f, 0.f};
    float m_run = -1e30f, l_run = 0.f;
    const int gq = qt * 64 + w * 16 + lr;

    for (int kt = 0; kt <= qt; ++kt) {
        __syncthreads();
#pragma unroll
        for (int i = 0; i < 2; ++i) {
            int cid = tid + 256 * i;          // 512 chunks: 64 rows x 8 col-chunks
            int r = cid >> 3, c8 = (cid & 7) * 8;
            const bf16* kvrow = QKV + (size_t)(b * 1024 + kt * 64 + r) * 3072 + h * 64;
            *(bf16x8*)(Ks + r * 72 + c8) = *(const bf16x8*)(kvrow + 1024 + c8);
            bf16x8 vv = *(const bf16x8*)(kvrow + 2048 + c8);
#pragma unroll
            for (int ii = 0; ii < 8; ++ii) Vt[(c8 + ii) * 72 + r] = vv[ii];
        }
        __syncthreads();

        f32x4 st[4];
#pragma unroll
        for (int i = 0; i < 4; ++i) st[i] = (f32x4){0.f, 0.f, 0.f, 0.f};
#pragma unroll
        for (int ki = 0; ki < 4; ++ki) {
            bf16x8 kf0 = *(const bf16x8*)(Ks + (ki * 16 + lr) * 72 + lg * 8);
            bf16x8 kf1 = *(const bf16x8*)(Ks + (ki * 16 + lr) * 72 + 32 + lg * 8);
            st[ki] = MFMA16(kf0, qf0, st[ki]);
            st[ki] = MFMA16(kf1, qf1, st[ki]);
        }
        bool diag = (kt == qt);
        float pm = -1e30f;
#pragma unroll
        for (int ki = 0; ki < 4; ++ki) {
#pragma unroll
            for (int j = 0; j < 4; ++j) {
                float sv = st[ki][j] * 0.125f;
                if (diag) {
                    int gk = kt * 64 + ki * 16 + lg * 4 + j;
                    if (gk > gq) sv = -1e30f;
                }
                st[ki][j] = sv;
                pm = fmaxf(pm, sv);
            }
        }
        pm = fmaxf(pm, __shfl_xor(pm, 16));
        pm = fmaxf(pm, __shfl_xor(pm, 32));
        float m_new = fmaxf(m_run, pm);
        float alpha = __expf(m_run - m_new);
        float rs = 0.f;
#pragma unroll
        for (int ki = 0; ki < 4; ++ki) {
            bf16x4 pb;
#pragma unroll
            for (int j = 0; j < 4; ++j) {
                float pv = __expf(st[ki][j] - m_new);
                rs += pv;
                pb[j] = (bf16)pv;
            }
            *(bf16x4*)(Pw + lr * 72 + ki * 16 + lg * 4) = pb;
        }
        rs += __shfl_xor(rs, 16);
        rs += __shfl_xor(rs, 32);
        l_run = l_run * alpha + rs;
        m_run = m_new;
#pragma unroll
        for (int di = 0; di < 4; ++di) o[di] *= alpha;
#pragma unroll
        for (int dk = 0; dk < 2; ++dk) {
            bf16x8 pf = *(const bf16x8*)(Pw + lr * 72 + dk * 32 + lg * 8);
#pragma unroll
            for (int di = 0; di < 4; ++di) {
                bf16x8 vf = *(const bf16x8*)(Vt + (di * 16 + lr) * 72 + dk * 32 + lg * 8);
                o[di] = MFMA16(vf, pf, o[di]);
            }
        }
    }
    float inv = 1.0f / l_run;
    bf16* optr = AO + (size_t)qrow * 1024 + h * 64;
#pragma unroll
    for (int di = 0; di < 4; ++di) {
        bf16x4 ov;
#pragma unroll
        for (int j = 0; j < 4; ++j) ov[j] = (bf16)(o[di][j] * inv);
        *(bf16x4*)(optr + di * 16 + lg * 4) = ov;
    }
}

// ---------------- driver ----------------

extern "C" void kernel_launch(void* const* d_in, const int* in_sizes, int n_in,
                              void* d_out, int out_size, void* d_ws, size_t ws_size,
                              hipStream_t stream) {
    const int* tokens = (const int*)d_in[0];
    const float* embed_w = (const float*)d_in[1];
    const float* qkv_w = (const float*)d_in[2];
    const float* o_w = (const float*)d_in[3];
    const float* gate_w = (const float*)d_in[4];
    const float* up_w = (const float*)d_in[5];
    const float* down_w = (const float*)d_in[6];
    const float* norm1_w = (const float*)d_in[7];
    const float* norm2_w = (const float*)d_in[8];
    const float* scale_gamma = (const float*)d_in[9];
    const float* scale_beta = (const float*)d_in[10];
    const float* iter_scale = (const float*)d_in[11];
    const float* norm_w = (const float*)d_in[12];
    const float* lm_head_w = (const float*)d_in[13];

    char* p = (char*)d_ws;
    auto alloc = [&](size_t nbytes) -> char* {
        char* r = p;
        p += (nbytes + 255) & ~(size_t)255;
        return r;
    };
    bf16* WQKV = (bf16*)alloc(3072ull * 1024 * 2);
    bf16* WO   = (bf16*)alloc(1024ull * 1024 * 2);
    bf16* WG   = (bf16*)alloc(2048ull * 1024 * 2);
    bf16* WU   = (bf16*)alloc(2048ull * 1024 * 2);
    bf16* WD   = (bf16*)alloc(1024ull * 2048 * 2);
    bf16* WLM  = (bf16*)alloc(32000ull * 1024 * 2);
    float* X   = (float*)alloc(2048ull * 1024 * 4);
    float* X1  = (float*)alloc(2048ull * 1024 * 4);
    bf16* H    = (bf16*)alloc(2048ull * 1024 * 2);
    bf16* QKVb = (bf16*)alloc(2048ull * 3072 * 2);
    bf16* AO   = (bf16*)alloc(2048ull * 1024 * 2);
    bf16* FF   = (bf16*)alloc(2048ull * 2048 * 2);

    cvt_kernel<<<1024, 256, 0, stream>>>(qkv_w, WQKV, 3072 * 1024 / 4);
    cvt_kernel<<<1024, 256, 0, stream>>>(o_w, WO, 1024 * 1024 / 4);
    cvt_kernel<<<1024, 256, 0, stream>>>(gate_w, WG, 2048 * 1024 / 4);
    cvt_kernel<<<1024, 256, 0, stream>>>(up_w, WU, 2048 * 1024 / 4);
    cvt_kernel<<<1024, 256, 0, stream>>>(down_w, WD, 1024 * 2048 / 4);
    cvt_kernel<<<2048, 256, 0, stream>>>(lm_head_w, WLM, 32000 * 1024 / 4);
    embed_kernel<<<2048, 256, 0, stream>>>(tokens, embed_w, X);

    for (int l = 0; l < 32; ++l) {
        const float* gm = scale_gamma + (size_t)(l >> 3) * 1024;
        const float* bt = scale_beta + (size_t)(l >> 3) * 1024;
        rmsnorm_kernel<true><<<2048, 256, 0, stream>>>(X, norm1_w, gm, bt, H);
        gemm_bt<4, 0><<<dim3(24, 16), 256, 0, stream>>>(H, WQKV, 3072, 1024,
                                                        QKVb, nullptr, nullptr, nullptr, nullptr, nullptr);
        attn_kernel<<<dim3(16, 32), 256, 0, stream>>>(QKVb, AO);
        gemm_bt<2, 1><<<dim3(8, 32), 256, 0, stream>>>(AO, WO, 1024, 1024,
                                                       nullptr, nullptr, X, nullptr, X1, nullptr);
        rmsnorm_kernel<true><<<2048, 256, 0, stream>>>(X1, norm2_w, gm, bt, H);
        gemm_gateup<<<dim3(16, 16), 256, 0, stream>>>(H, WG, WU, FF);
        gemm_bt<2, 2><<<dim3(8, 32), 256, 0, stream>>>(FF, WD, 1024, 2048,
                                                       nullptr, nullptr, X, X1, X, iter_scale + l);
    }
    rmsnorm_kernel<false><<<2048, 256, 0, stream>>>(X, norm_w, nullptr, nullptr, H);
    gemm_bt<4, 3><<<dim3(250, 16), 256, 0, stream>>>(H, WLM, 32000, 1024,
                                                     nullptr, (float*)d_out, nullptr, nullptr, nullptr, nullptr);
}

// Round 4
// 5282.426 us; speedup vs baseline: 1.3704x; 1.0267x over previous
//
#include <hip/hip_runtime.h>

typedef __bf16 bf16;
typedef __attribute__((ext_vector_type(8))) __bf16 bf16x8;
typedef __attribute__((ext_vector_type(4))) __bf16 bf16x4;
typedef __attribute__((ext_vector_type(4))) float f32x4;

#define MFMA16(a,b,c) __builtin_amdgcn_mfma_f32_16x16x32_bf16((a),(b),(c),0,0,0)

__device__ __forceinline__ void gload16(const void* g, void* l) {
    __builtin_amdgcn_global_load_lds((const __attribute__((address_space(1))) void*)g,
                                     (__attribute__((address_space(3))) void*)l, 16, 0, 0);
}

// bijective XCD-chunked block swizzle (m204): each XCD owns a contiguous chunk
// of the logical block range, so panel reuse lands in one XCD's L2.
__device__ __forceinline__ int xcd_swizzle(int orig, int nwg) {
    int q = nwg >> 3, r = nwg & 7;
    int xcd = orig & 7, loc = orig >> 3;
    int base = (xcd < r) ? xcd * (q + 1) : r * (q + 1) + (xcd - r) * q;
    return base + loc;
}

// ---------------- elementwise / small kernels ----------------

__global__ __launch_bounds__(256) void cvt_kernel(const float* __restrict__ in,
                                                  bf16* __restrict__ out, int n4) {
    int stride = gridDim.x * 256;
    for (int i = blockIdx.x * 256 + threadIdx.x; i < n4; i += stride) {
        float4 v = ((const float4*)in)[i];
        bf16x4 o;
        o[0] = (bf16)v.x; o[1] = (bf16)v.y; o[2] = (bf16)v.z; o[3] = (bf16)v.w;
        ((bf16x4*)out)[i] = o;
    }
}

__global__ __launch_bounds__(256) void embed_kernel(const int* __restrict__ tok,
                                                    const float* __restrict__ ew,
                                                    float* __restrict__ X) {
    int m = blockIdx.x;
    int t = tok[m];
    ((float4*)(X + (size_t)m * 1024))[threadIdx.x] =
        ((const float4*)(ew + (size_t)t * 1024))[threadIdx.x];
}

template <bool FILM>
__global__ __launch_bounds__(256) void rmsnorm_kernel(const float* __restrict__ X,
                                                      const float* __restrict__ w,
                                                      const float* __restrict__ gamma,
                                                      const float* __restrict__ beta,
                                                      bf16* __restrict__ H) {
    int m = blockIdx.x, t = threadIdx.x;
    float4 xv = ((const float4*)(X + (size_t)m * 1024))[t];
    float ss = xv.x * xv.x + xv.y * xv.y + xv.z * xv.z + xv.w * xv.w;
#pragma unroll
    for (int off = 1; off < 64; off <<= 1) ss += __shfl_xor(ss, off);
    __shared__ float red[4];
    if ((t & 63) == 0) red[t >> 6] = ss;
    __syncthreads();
    float tot = red[0] + red[1] + red[2] + red[3];
    float sc = rsqrtf(tot * (1.0f / 1024.0f) + 1.1920929e-07f);
    float4 wv = ((const float4*)w)[t];
    float r0 = xv.x * sc * wv.x, r1 = xv.y * sc * wv.y;
    float r2 = xv.z * sc * wv.z, r3 = xv.w * sc * wv.w;
    if (FILM) {
        float4 gv = ((const float4*)gamma)[t];
        float4 bv = ((const float4*)beta)[t];
        r0 = r0 * gv.x + bv.x; r1 = r1 * gv.y + bv.y;
        r2 = r2 * gv.z + bv.z; r3 = r3 * gv.w + bv.w;
    }
    bf16x4 o;
    o[0] = (bf16)r0; o[1] = (bf16)r1; o[2] = (bf16)r2; o[3] = (bf16)r3;
    ((bf16x4*)(H + (size_t)m * 1024))[t] = o;
}

// ---------------- GEMM: C[M,N] = A[M,K] @ B[N,K]^T, global_load_lds staging ----------------
// 1D grid of GN*GM blocks, XCD-chunk-swizzled.
// BNF=true: bn varies fastest within a chunk (A panels read once per XCD; use when A larger)
// BNF=false: bm varies fastest (B panels read once per XCD; use when B larger)
// MODE 0: Cb = bf16(acc)
// MODE 1: Xout = Xin + acc                       (o-proj residual)
// MODE 2: Xout = Xin + s*((Xin2-Xin) + acc)      (fractal update)
// MODE 3: Cf = acc                               (lm_head, f32 out)

template <int MT, int MODE, bool BNF>
__global__ __launch_bounds__(256, 2) void gemm_bt(const bf16* __restrict__ A,
                                                  const bf16* __restrict__ B,
                                                  int GN, int GM,
                                                  int N, int K,
                                                  bf16* __restrict__ Cb, float* __restrict__ Cf,
                                                  const float* __restrict__ Xin,
                                                  const float* __restrict__ Xin2,
                                                  float* __restrict__ Xout,
                                                  const float* __restrict__ sptr) {
    constexpr int BM = 32 * MT;
    __shared__ __align__(16) bf16 As[BM * 64];
    __shared__ __align__(16) bf16 Bs[128 * 64];
    const int wg = xcd_swizzle(blockIdx.x, GN * GM);
    int bn, bm;
    if (BNF) { bm = wg / GN; bn = wg - bm * GN; }
    else     { bn = wg / GM; bm = wg - bn * GM; }
    const int tid = threadIdx.x, lane = tid & 63, w = tid >> 6;
    const int wr = w >> 1, wc = w & 1, lr = lane & 15, lg = lane >> 4;
    const bf16* Ab = A + (size_t)bm * BM * K;
    const bf16* Bb = B + (size_t)bn * 128 * K;

    f32x4 acc[MT][4];
#pragma unroll
    for (int i = 0; i < MT; ++i)
#pragma unroll
        for (int j = 0; j < 4; ++j) acc[i][j] = (f32x4){0.f, 0.f, 0.f, 0.f};

    for (int kt = 0; kt < K; kt += 64) {
        __syncthreads();
#pragma unroll
        for (int i = 0; i < MT; ++i) {
            int cw = i * 256 + w * 64;
            int cid = cw + lane;
            gload16(Ab + (size_t)(cid >> 3) * K + kt + (cid & 7) * 8, As + cw * 8);
        }
#pragma unroll
        for (int i = 0; i < 4; ++i) {
            int cw = i * 256 + w * 64;
            int cid = cw + lane;
            gload16(Bb + (size_t)(cid >> 3) * K + kt + (cid & 7) * 8, Bs + cw * 8);
        }
        __syncthreads();
#pragma unroll
        for (int kk = 0; kk < 64; kk += 32) {
            bf16x8 af[MT], bfr[4];
#pragma unroll
            for (int mi = 0; mi < MT; ++mi)
                af[mi] = *(const bf16x8*)(As + (wr * (16 * MT) + mi * 16 + lr) * 64 + kk + lg * 8);
#pragma unroll
            for (int ni = 0; ni < 4; ++ni)
                bfr[ni] = *(const bf16x8*)(Bs + (wc * 64 + ni * 16 + lr) * 64 + kk + lg * 8);
#pragma unroll
            for (int mi = 0; mi < MT; ++mi)
#pragma unroll
                for (int ni = 0; ni < 4; ++ni)
                    acc[mi][ni] = MFMA16(af[mi], bfr[ni], acc[mi][ni]);
        }
    }

    float s1 = (MODE == 2) ? sptr[0] : 0.f;
#pragma unroll
    for (int mi = 0; mi < MT; ++mi) {
#pragma unroll
        for (int ni = 0; ni < 4; ++ni) {
#pragma unroll
            for (int j = 0; j < 4; ++j) {
                int row = bm * BM + wr * (16 * MT) + mi * 16 + lg * 4 + j;
                int col = bn * 128 + wc * 64 + ni * 16 + lr;
                size_t idx = (size_t)row * N + col;
                float v = acc[mi][ni][j];
                if (MODE == 0) Cb[idx] = (bf16)v;
                else if (MODE == 1) Xout[idx] = Xin[idx] + v;
                else if (MODE == 2) Xout[idx] = Xin[idx] + s1 * (Xin2[idx] - Xin[idx] + v);
                else Cf[idx] = v;
            }
        }
    }
}

// ---------------- fused gate+up GEMM with SwiGLU epilogue ----------------
// FF[2048,2048] = silu(H @ Wg^T) * (H @ Wu^T), K=1024. Tile 128x128, dual acc.
// 1D grid 16x16, bm-fastest (B = gate+up = 8MB is the larger operand).

__global__ __launch_bounds__(256, 2) void gemm_gateup(const bf16* __restrict__ A,
                                                      const bf16* __restrict__ Bg,
                                                      const bf16* __restrict__ Bu,
                                                      bf16* __restrict__ FF) {
    const int K = 1024, N = 2048;
    __shared__ __align__(16) bf16 As[128 * 64];
    __shared__ __align__(16) bf16 Gs[128 * 64];
    __shared__ __align__(16) bf16 Us[128 * 64];
    const int wg = xcd_swizzle(blockIdx.x, 256);
    const int bn = wg >> 4, bm = wg & 15;
    const int tid = threadIdx.x, lane = tid & 63, w = tid >> 6;
    const int wr = w >> 1, wc = w & 1, lr = lane & 15, lg = lane >> 4;
    const bf16* Ab = A + (size_t)bm * 128 * K;
    const bf16* Gb = Bg + (size_t)bn * 128 * K;
    const bf16* Ub = Bu + (size_t)bn * 128 * K;

    f32x4 ag[4][4], au[4][4];
#pragma unroll
    for (int i = 0; i < 4; ++i)
#pragma unroll
        for (int j = 0; j < 4; ++j) {
            ag[i][j] = (f32x4){0.f, 0.f, 0.f, 0.f};
            au[i][j] = (f32x4){0.f, 0.f, 0.f, 0.f};
        }

    for (int kt = 0; kt < K; kt += 64) {
        __syncthreads();
#pragma unroll
        for (int i = 0; i < 4; ++i) {
            int cw = i * 256 + w * 64;
            int cid = cw + lane;
            size_t ro = (size_t)(cid >> 3) * K + kt + (cid & 7) * 8;
            gload16(Ab + ro, As + cw * 8);
            gload16(Gb + ro, Gs + cw * 8);
            gload16(Ub + ro, Us + cw * 8);
        }
        __syncthreads();
#pragma unroll
        for (int kk = 0; kk < 64; kk += 32) {
            bf16x8 af[4], gf[4], uf[4];
#pragma unroll
            for (int mi = 0; mi < 4; ++mi)
                af[mi] = *(const bf16x8*)(As + (wr * 64 + mi * 16 + lr) * 64 + kk + lg * 8);
#pragma unroll
            for (int ni = 0; ni < 4; ++ni) {
                gf[ni] = *(const bf16x8*)(Gs + (wc * 64 + ni * 16 + lr) * 64 + kk + lg * 8);
                uf[ni] = *(const bf16x8*)(Us + (wc * 64 + ni * 16 + lr) * 64 + kk + lg * 8);
            }
#pragma unroll
            for (int mi = 0; mi < 4; ++mi)
#pragma unroll
                for (int ni = 0; ni < 4; ++ni) {
                    ag[mi][ni] = MFMA16(af[mi], gf[ni], ag[mi][ni]);
                    au[mi][ni] = MFMA16(af[mi], uf[ni], au[mi][ni]);
                }
        }
    }

#pragma unroll
    for (int mi = 0; mi < 4; ++mi) {
#pragma unroll
        for (int ni = 0; ni < 4; ++ni) {
#pragma unroll
            for (int j = 0; j < 4; ++j) {
                int row = bm * 128 + wr * 64 + mi * 16 + lg * 4 + j;
                int col = bn * 128 + wc * 64 + ni * 16 + lr;
                float g = ag[mi][ni][j], u = au[mi][ni][j];
                float sg = g / (1.0f + __expf(-g));
                FF[(size_t)row * N + col] = (bf16)(sg * u);
            }
        }
    }
}

// ---------------- causal flash attention (all-transposed form) ----------------

__global__ __launch_bounds__(256) void attn_kernel(const bf16* __restrict__ QKV,
                                                   bf16* __restrict__ AO) {
    const int qt = blockIdx.x, bh = blockIdx.y;
    const int b = bh >> 4, h = bh & 15;
    const int tid = threadIdx.x;
    const int w = tid >> 6, lane = tid & 63;
    const int lr = lane & 15, lg = lane >> 4;

    __shared__ __align__(16) bf16 Ks[64 * 72];
    __shared__ __align__(16) bf16 Vt[64 * 72];
    __shared__ __align__(16) bf16 Ps[4 * 16 * 72];
    bf16* Pw = Ps + w * 16 * 72;

    const int qrow = b * 1024 + qt * 64 + w * 16 + lr;
    const bf16* qptr = QKV + (size_t)qrow * 3072 + h * 64;
    bf16x8 qf0 = *(const bf16x8*)(qptr + lg * 8);
    bf16x8 qf1 = *(const bf16x8*)(qptr + 32 + lg * 8);

    f32x4 o[4];
#pragma unroll
    for (int i = 0; i < 4; ++i) o[i] = (f32x4){0.f, 0.f, 0.f, 0.f};
    float m_run = -1e30f, l_run = 0.f;
    const int gq = qt * 64 + w * 16 + lr;

    for (int kt = 0; kt <= qt; ++kt) {
        __syncthreads();
#pragma unroll
        for (int i = 0; i < 2; ++i) {
            int cid = tid + 256 * i;          // 512 chunks: 64 rows x 8 col-chunks
            int r = cid >> 3, c8 = (cid & 7) * 8;
            const bf16* kvrow = QKV + (size_t)(b * 1024 + kt * 64 + r) * 3072 + h * 64;
            *(bf16x8*)(Ks + r * 72 + c8) = *(const bf16x8*)(kvrow + 1024 + c8);
            bf16x8 vv = *(const bf16x8*)(kvrow + 2048 + c8);
#pragma unroll
            for (int ii = 0; ii < 8; ++ii) Vt[(c8 + ii) * 72 + r] = vv[ii];
        }
        __syncthreads();

        f32x4 st[4];
#pragma unroll
        for (int i = 0; i < 4; ++i) st[i] = (f32x4){0.f, 0.f, 0.f, 0.f};
        __builtin_amdgcn_s_setprio(1);
#pragma unroll
        for (int ki = 0; ki < 4; ++ki) {
            bf16x8 kf0 = *(const bf16x8*)(Ks + (ki * 16 + lr) * 72 + lg * 8);
            bf16x8 kf1 = *(const bf16x8*)(Ks + (ki * 16 + lr) * 72 + 32 + lg * 8);
            st[ki] = MFMA16(kf0, qf0, st[ki]);
            st[ki] = MFMA16(kf1, qf1, st[ki]);
        }
        __builtin_amdgcn_s_setprio(0);
        bool diag = (kt == qt);
        float pm = -1e30f;
#pragma unroll
        for (int ki = 0; ki < 4; ++ki) {
#pragma unroll
            for (int j = 0; j < 4; ++j) {
                float sv = st[ki][j] * 0.125f;
                if (diag) {
                    int gk = kt * 64 + ki * 16 + lg * 4 + j;
                    if (gk > gq) sv = -1e30f;
                }
                st[ki][j] = sv;
                pm = fmaxf(pm, sv);
            }
        }
        pm = fmaxf(pm, __shfl_xor(pm, 16));
        pm = fmaxf(pm, __shfl_xor(pm, 32));
        float m_new = fmaxf(m_run, pm);
        float alpha = __expf(m_run - m_new);
        float rs = 0.f;
#pragma unroll
        for (int ki = 0; ki < 4; ++ki) {
            bf16x4 pb;
#pragma unroll
            for (int j = 0; j < 4; ++j) {
                float pv = __expf(st[ki][j] - m_new);
                rs += pv;
                pb[j] = (bf16)pv;
            }
            *(bf16x4*)(Pw + lr * 72 + ki * 16 + lg * 4) = pb;
        }
        rs += __shfl_xor(rs, 16);
        rs += __shfl_xor(rs, 32);
        l_run = l_run * alpha + rs;
        m_run = m_new;
#pragma unroll
        for (int di = 0; di < 4; ++di) o[di] *= alpha;
        __builtin_amdgcn_s_setprio(1);
#pragma unroll
        for (int dk = 0; dk < 2; ++dk) {
            bf16x8 pf = *(const bf16x8*)(Pw + lr * 72 + dk * 32 + lg * 8);
#pragma unroll
            for (int di = 0; di < 4; ++di) {
                bf16x8 vf = *(const bf16x8*)(Vt + (di * 16 + lr) * 72 + dk * 32 + lg * 8);
                o[di] = MFMA16(vf, pf, o[di]);
            }
        }
        __builtin_amdgcn_s_setprio(0);
    }
    float inv = 1.0f / l_run;
    bf16* optr = AO + (size_t)qrow * 1024 + h * 64;
#pragma unroll
    for (int di = 0; di < 4; ++di) {
        bf16x4 ov;
#pragma unroll
        for (int j = 0; j < 4; ++j) ov[j] = (bf16)(o[di][j] * inv);
        *(bf16x4*)(optr + di * 16 + lg * 4) = ov;
    }
}

// ---------------- driver ----------------

extern "C" void kernel_launch(void* const* d_in, const int* in_sizes, int n_in,
                              void* d_out, int out_size, void* d_ws, size_t ws_size,
                              hipStream_t stream) {
    const int* tokens = (const int*)d_in[0];
    const float* embed_w = (const float*)d_in[1];
    const float* qkv_w = (const float*)d_in[2];
    const float* o_w = (const float*)d_in[3];
    const float* gate_w = (const float*)d_in[4];
    const float* up_w = (const float*)d_in[5];
    const float* down_w = (const float*)d_in[6];
    const float* norm1_w = (const float*)d_in[7];
    const float* norm2_w = (const float*)d_in[8];
    const float* scale_gamma = (const float*)d_in[9];
    const float* scale_beta = (const float*)d_in[10];
    const float* iter_scale = (const float*)d_in[11];
    const float* norm_w = (const float*)d_in[12];
    const float* lm_head_w = (const float*)d_in[13];

    char* p = (char*)d_ws;
    auto alloc = [&](size_t nbytes) -> char* {
        char* r = p;
        p += (nbytes + 255) & ~(size_t)255;
        return r;
    };
    bf16* WQKV = (bf16*)alloc(3072ull * 1024 * 2);
    bf16* WO   = (bf16*)alloc(1024ull * 1024 * 2);
    bf16* WG   = (bf16*)alloc(2048ull * 1024 * 2);
    bf16* WU   = (bf16*)alloc(2048ull * 1024 * 2);
    bf16* WD   = (bf16*)alloc(1024ull * 2048 * 2);
    bf16* WLM  = (bf16*)alloc(32000ull * 1024 * 2);
    float* X   = (float*)alloc(2048ull * 1024 * 4);
    float* X1  = (float*)alloc(2048ull * 1024 * 4);
    bf16* H    = (bf16*)alloc(2048ull * 1024 * 2);
    bf16* QKVb = (bf16*)alloc(2048ull * 3072 * 2);
    bf16* AO   = (bf16*)alloc(2048ull * 1024 * 2);
    bf16* FF   = (bf16*)alloc(2048ull * 2048 * 2);

    cvt_kernel<<<1024, 256, 0, stream>>>(qkv_w, WQKV, 3072 * 1024 / 4);
    cvt_kernel<<<1024, 256, 0, stream>>>(o_w, WO, 1024 * 1024 / 4);
    cvt_kernel<<<1024, 256, 0, stream>>>(gate_w, WG, 2048 * 1024 / 4);
    cvt_kernel<<<1024, 256, 0, stream>>>(up_w, WU, 2048 * 1024 / 4);
    cvt_kernel<<<1024, 256, 0, stream>>>(down_w, WD, 1024 * 2048 / 4);
    cvt_kernel<<<2048, 256, 0, stream>>>(lm_head_w, WLM, 32000 * 1024 / 4);
    embed_kernel<<<2048, 256, 0, stream>>>(tokens, embed_w, X);

    for (int l = 0; l < 32; ++l) {
        const float* gm = scale_gamma + (size_t)(l >> 3) * 1024;
        const float* bt = scale_beta + (size_t)(l >> 3) * 1024;
        rmsnorm_kernel<true><<<2048, 256, 0, stream>>>(X, norm1_w, gm, bt, H);
        // QKV: B=6MB > A=4MB -> bm-fastest
        gemm_bt<4, 0, false><<<24 * 16, 256, 0, stream>>>(H, WQKV, 24, 16, 3072, 1024,
                                                          QKVb, nullptr, nullptr, nullptr, nullptr, nullptr);
        attn_kernel<<<dim3(16, 32), 256, 0, stream>>>(QKVb, AO);
        // o-proj: A=4MB > B=2MB -> bn-fastest
        gemm_bt<2, 1, true><<<8 * 32, 256, 0, stream>>>(AO, WO, 8, 32, 1024, 1024,
                                                        nullptr, nullptr, X, nullptr, X1, nullptr);
        rmsnorm_kernel<true><<<2048, 256, 0, stream>>>(X1, norm2_w, gm, bt, H);
        gemm_gateup<<<256, 256, 0, stream>>>(H, WG, WU, FF);
        // down: A=8MB > B=4MB -> bn-fastest
        gemm_bt<2, 2, true><<<8 * 32, 256, 0, stream>>>(FF, WD, 8, 32, 1024, 2048,
                                                        nullptr, nullptr, X, X1, X, iter_scale + l);
    }
    rmsnorm_kernel<false><<<2048, 256, 0, stream>>>(X, norm_w, nullptr, nullptr, H);
    // lm_head: B=65MB >> A=4MB -> bm-fastest
    gemm_bt<4, 3, false><<<250 * 16, 256, 0, stream>>>(H, WLM, 250, 16, 32000, 1024,
                                                       nullptr, (float*)d_out, nullptr, nullptr, nullptr, nullptr);
}

// Round 5
// 5057.408 us; speedup vs baseline: 1.4314x; 1.0445x over previous
//
#include <hip/hip_runtime.h>

typedef __bf16 bf16;
typedef __attribute__((ext_vector_type(8))) __bf16 bf16x8;
typedef __attribute__((ext_vector_type(4))) __bf16 bf16x4;
typedef __attribute__((ext_vector_type(4))) float f32x4;

#define MFMA16(a,b,c) __builtin_amdgcn_mfma_f32_16x16x32_bf16((a),(b),(c),0,0,0)

__device__ __forceinline__ void gload16(const void* g, void* l) {
    __builtin_amdgcn_global_load_lds((const __attribute__((address_space(1))) void*)g,
                                     (__attribute__((address_space(3))) void*)l, 16, 0, 0);
}

// bijective XCD-chunked block swizzle (m204): each XCD owns a contiguous chunk
// of the logical block range, so panel reuse lands in one XCD's L2.
__device__ __forceinline__ int xcd_swizzle(int orig, int nwg) {
    int q = nwg >> 3, r = nwg & 7;
    int xcd = orig & 7, loc = orig >> 3;
    int base = (xcd < r) ? xcd * (q + 1) : r * (q + 1) + (xcd - r) * q;
    return base + loc;
}

// ---------------- elementwise / small kernels ----------------

__global__ __launch_bounds__(256) void cvt_kernel(const float* __restrict__ in,
                                                  bf16* __restrict__ out, int n4) {
    int stride = gridDim.x * 256;
    for (int i = blockIdx.x * 256 + threadIdx.x; i < n4; i += stride) {
        float4 v = ((const float4*)in)[i];
        bf16x4 o;
        o[0] = (bf16)v.x; o[1] = (bf16)v.y; o[2] = (bf16)v.z; o[3] = (bf16)v.w;
        ((bf16x4*)out)[i] = o;
    }
}

__global__ __launch_bounds__(256) void embed_kernel(const int* __restrict__ tok,
                                                    const float* __restrict__ ew,
                                                    float* __restrict__ X) {
    int m = blockIdx.x;
    int t = tok[m];
    ((float4*)(X + (size_t)m * 1024))[threadIdx.x] =
        ((const float4*)(ew + (size_t)t * 1024))[threadIdx.x];
}

template <bool FILM>
__global__ __launch_bounds__(256) void rmsnorm_kernel(const float* __restrict__ X,
                                                      const float* __restrict__ w,
                                                      const float* __restrict__ gamma,
                                                      const float* __restrict__ beta,
                                                      bf16* __restrict__ H) {
    int m = blockIdx.x, t = threadIdx.x;
    float4 xv = ((const float4*)(X + (size_t)m * 1024))[t];
    float ss = xv.x * xv.x + xv.y * xv.y + xv.z * xv.z + xv.w * xv.w;
#pragma unroll
    for (int off = 1; off < 64; off <<= 1) ss += __shfl_xor(ss, off);
    __shared__ float red[4];
    if ((t & 63) == 0) red[t >> 6] = ss;
    __syncthreads();
    float tot = red[0] + red[1] + red[2] + red[3];
    float sc = rsqrtf(tot * (1.0f / 1024.0f) + 1.1920929e-07f);
    float4 wv = ((const float4*)w)[t];
    float r0 = xv.x * sc * wv.x, r1 = xv.y * sc * wv.y;
    float r2 = xv.z * sc * wv.z, r3 = xv.w * sc * wv.w;
    if (FILM) {
        float4 gv = ((const float4*)gamma)[t];
        float4 bv = ((const float4*)beta)[t];
        r0 = r0 * gv.x + bv.x; r1 = r1 * gv.y + bv.y;
        r2 = r2 * gv.z + bv.z; r3 = r3 * gv.w + bv.w;
    }
    bf16x4 o;
    o[0] = (bf16)r0; o[1] = (bf16)r1; o[2] = (bf16)r2; o[3] = (bf16)r3;
    ((bf16x4*)(H + (size_t)m * 1024))[t] = o;
}

// ---------------- V pre-transpose: VT[b*16+h][d][t] = V[b,t,h,d] ----------------
// One 64x64 tile per block; LDS-tiled so both global sides are vectorized.

__global__ __launch_bounds__(256) void vtrans_kernel(const bf16* __restrict__ QKV,
                                                     bf16* __restrict__ VT) {
    const int tt = blockIdx.x, bh = blockIdx.y;
    const int b = bh >> 4, h = bh & 15;
    __shared__ __align__(16) bf16 Ls[64 * 72];
    const int tid = threadIdx.x;
#pragma unroll
    for (int i = 0; i < 2; ++i) {
        int cid = tid + 256 * i;
        int r = cid >> 3, c8 = (cid & 7) * 8;
        *(bf16x8*)(Ls + r * 72 + c8) =
            *(const bf16x8*)(QKV + (size_t)(b * 1024 + tt * 64 + r) * 3072 + 2048 + h * 64 + c8);
    }
    __syncthreads();
#pragma unroll
    for (int i = 0; i < 2; ++i) {
        int cid = tid + 256 * i;
        int d = cid >> 3, k8 = (cid & 7) * 8;
        bf16x8 v;
#pragma unroll
        for (int j = 0; j < 8; ++j) v[j] = Ls[(k8 + j) * 72 + d];
        *(bf16x8*)(VT + (size_t)bh * 65536 + (size_t)d * 1024 + tt * 64 + k8) = v;
    }
}

// ---------------- GEMM: C[M,N] = A[M,K] @ B[N,K]^T, global_load_lds staging ----------------
// MODE 0: Cb = bf16(acc)
// MODE 1: Xout = Xin + acc                       (o-proj residual)
// MODE 2: Xout = Xin + s*((Xin2-Xin) + acc)      (fractal update)
// MODE 3: Cf = acc                               (lm_head, f32 out)

template <int MT, int MODE, bool BNF>
__global__ __launch_bounds__(256, 2) void gemm_bt(const bf16* __restrict__ A,
                                                  const bf16* __restrict__ B,
                                                  int GN, int GM,
                                                  int N, int K,
                                                  bf16* __restrict__ Cb, float* __restrict__ Cf,
                                                  const float* __restrict__ Xin,
                                                  const float* __restrict__ Xin2,
                                                  float* __restrict__ Xout,
                                                  const float* __restrict__ sptr) {
    constexpr int BM = 32 * MT;
    __shared__ __align__(16) bf16 As[BM * 64];
    __shared__ __align__(16) bf16 Bs[128 * 64];
    const int wg = xcd_swizzle(blockIdx.x, GN * GM);
    int bn, bm;
    if (BNF) { bm = wg / GN; bn = wg - bm * GN; }
    else     { bn = wg / GM; bm = wg - bn * GM; }
    const int tid = threadIdx.x, lane = tid & 63, w = tid >> 6;
    const int wr = w >> 1, wc = w & 1, lr = lane & 15, lg = lane >> 4;
    const bf16* Ab = A + (size_t)bm * BM * K;
    const bf16* Bb = B + (size_t)bn * 128 * K;

    f32x4 acc[MT][4];
#pragma unroll
    for (int i = 0; i < MT; ++i)
#pragma unroll
        for (int j = 0; j < 4; ++j) acc[i][j] = (f32x4){0.f, 0.f, 0.f, 0.f};

    for (int kt = 0; kt < K; kt += 64) {
        __syncthreads();
#pragma unroll
        for (int i = 0; i < MT; ++i) {
            int cw = i * 256 + w * 64;
            int cid = cw + lane;
            gload16(Ab + (size_t)(cid >> 3) * K + kt + (cid & 7) * 8, As + cw * 8);
        }
#pragma unroll
        for (int i = 0; i < 4; ++i) {
            int cw = i * 256 + w * 64;
            int cid = cw + lane;
            gload16(Bb + (size_t)(cid >> 3) * K + kt + (cid & 7) * 8, Bs + cw * 8);
        }
        __syncthreads();
#pragma unroll
        for (int kk = 0; kk < 64; kk += 32) {
            bf16x8 af[MT], bfr[4];
#pragma unroll
            for (int mi = 0; mi < MT; ++mi)
                af[mi] = *(const bf16x8*)(As + (wr * (16 * MT) + mi * 16 + lr) * 64 + kk + lg * 8);
#pragma unroll
            for (int ni = 0; ni < 4; ++ni)
                bfr[ni] = *(const bf16x8*)(Bs + (wc * 64 + ni * 16 + lr) * 64 + kk + lg * 8);
#pragma unroll
            for (int mi = 0; mi < MT; ++mi)
#pragma unroll
                for (int ni = 0; ni < 4; ++ni)
                    acc[mi][ni] = MFMA16(af[mi], bfr[ni], acc[mi][ni]);
        }
    }

    float s1 = (MODE == 2) ? sptr[0] : 0.f;
#pragma unroll
    for (int mi = 0; mi < MT; ++mi) {
#pragma unroll
        for (int ni = 0; ni < 4; ++ni) {
#pragma unroll
            for (int j = 0; j < 4; ++j) {
                int row = bm * BM + wr * (16 * MT) + mi * 16 + lg * 4 + j;
                int col = bn * 128 + wc * 64 + ni * 16 + lr;
                size_t idx = (size_t)row * N + col;
                float v = acc[mi][ni][j];
                if (MODE == 0) Cb[idx] = (bf16)v;
                else if (MODE == 1) Xout[idx] = Xin[idx] + v;
                else if (MODE == 2) Xout[idx] = Xin[idx] + s1 * (Xin2[idx] - Xin[idx] + v);
                else Cf[idx] = v;
            }
        }
    }
}

// ---------------- fused gate+up GEMM with SwiGLU epilogue ----------------

__global__ __launch_bounds__(256, 2) void gemm_gateup(const bf16* __restrict__ A,
                                                      const bf16* __restrict__ Bg,
                                                      const bf16* __restrict__ Bu,
                                                      bf16* __restrict__ FF) {
    const int K = 1024, N = 2048;
    __shared__ __align__(16) bf16 As[128 * 64];
    __shared__ __align__(16) bf16 Gs[128 * 64];
    __shared__ __align__(16) bf16 Us[128 * 64];
    const int wg = xcd_swizzle(blockIdx.x, 256);
    const int bn = wg >> 4, bm = wg & 15;
    const int tid = threadIdx.x, lane = tid & 63, w = tid >> 6;
    const int wr = w >> 1, wc = w & 1, lr = lane & 15, lg = lane >> 4;
    const bf16* Ab = A + (size_t)bm * 128 * K;
    const bf16* Gb = Bg + (size_t)bn * 128 * K;
    const bf16* Ub = Bu + (size_t)bn * 128 * K;

    f32x4 ag[4][4], au[4][4];
#pragma unroll
    for (int i = 0; i < 4; ++i)
#pragma unroll
        for (int j = 0; j < 4; ++j) {
            ag[i][j] = (f32x4){0.f, 0.f, 0.f, 0.f};
            au[i][j] = (f32x4){0.f, 0.f, 0.f, 0.f};
        }

    for (int kt = 0; kt < K; kt += 64) {
        __syncthreads();
#pragma unroll
        for (int i = 0; i < 4; ++i) {
            int cw = i * 256 + w * 64;
            int cid = cw + lane;
            size_t ro = (size_t)(cid >> 3) * K + kt + (cid & 7) * 8;
            gload16(Ab + ro, As + cw * 8);
            gload16(Gb + ro, Gs + cw * 8);
            gload16(Ub + ro, Us + cw * 8);
        }
        __syncthreads();
#pragma unroll
        for (int kk = 0; kk < 64; kk += 32) {
            bf16x8 af[4], gf[4], uf[4];
#pragma unroll
            for (int mi = 0; mi < 4; ++mi)
                af[mi] = *(const bf16x8*)(As + (wr * 64 + mi * 16 + lr) * 64 + kk + lg * 8);
#pragma unroll
            for (int ni = 0; ni < 4; ++ni) {
                gf[ni] = *(const bf16x8*)(Gs + (wc * 64 + ni * 16 + lr) * 64 + kk + lg * 8);
                uf[ni] = *(const bf16x8*)(Us + (wc * 64 + ni * 16 + lr) * 64 + kk + lg * 8);
            }
#pragma unroll
            for (int mi = 0; mi < 4; ++mi)
#pragma unroll
                for (int ni = 0; ni < 4; ++ni) {
                    ag[mi][ni] = MFMA16(af[mi], gf[ni], ag[mi][ni]);
                    au[mi][ni] = MFMA16(af[mi], uf[ni], au[mi][ni]);
                }
        }
    }

#pragma unroll
    for (int mi = 0; mi < 4; ++mi) {
#pragma unroll
        for (int ni = 0; ni < 4; ++ni) {
#pragma unroll
            for (int j = 0; j < 4; ++j) {
                int row = bm * 128 + wr * 64 + mi * 16 + lg * 4 + j;
                int col = bn * 128 + wc * 64 + ni * 16 + lr;
                float g = ag[mi][ni][j], u = au[mi][ni][j];
                float sg = g / (1.0f + __expf(-g));
                FF[(size_t)row * N + col] = (bf16)(sg * u);
            }
        }
    }
}

// ---------------- causal flash attention (all-transposed form, VT pre-transposed) ----------------

__global__ __launch_bounds__(256) void attn_kernel(const bf16* __restrict__ QKV,
                                                   const bf16* __restrict__ VTg,
                                                   bf16* __restrict__ AO) {
    const int qt = blockIdx.x, bh = blockIdx.y;
    const int b = bh >> 4, h = bh & 15;
    const int tid = threadIdx.x;
    const int w = tid >> 6, lane = tid & 63;
    const int lr = lane & 15, lg = lane >> 4;

    __shared__ __align__(16) bf16 Ks[64 * 72];
    __shared__ __align__(16) bf16 Vt[64 * 72];
    __shared__ __align__(16) bf16 Ps[4 * 16 * 72];
    bf16* Pw = Ps + w * 16 * 72;

    const int qrow = b * 1024 + qt * 64 + w * 16 + lr;
    const bf16* qptr = QKV + (size_t)qrow * 3072 + h * 64;
    const bf16* vt_src = VTg + (size_t)bh * 65536;
    bf16x8 qf0 = *(const bf16x8*)(qptr + lg * 8);
    bf16x8 qf1 = *(const bf16x8*)(qptr + 32 + lg * 8);

    f32x4 o[4];
#pragma unroll
    for (int i = 0; i < 4; ++i) o[i] = (f32x4){0.f, 0.f, 0.f, 0.f};
    float m_run = -1e30f, l_run = 0.f;
    const int gq = qt * 64 + w * 16 + lr;

    for (int kt = 0; kt <= qt; ++kt) {
        __syncthreads();
#pragma unroll
        for (int i = 0; i < 2; ++i) {
            int cid = tid + 256 * i;          // 512 chunks: 64 rows x 8 col-chunks
            int r = cid >> 3, c8 = (cid & 7) * 8;
            const bf16* kvrow = QKV + (size_t)(b * 1024 + kt * 64 + r) * 3072 + h * 64;
            *(bf16x8*)(Ks + r * 72 + c8) = *(const bf16x8*)(kvrow + 1024 + c8);
            *(bf16x8*)(Vt + r * 72 + c8) =
                *(const bf16x8*)(vt_src + (size_t)r * 1024 + kt * 64 + c8);
        }
        __syncthreads();

        f32x4 st[4];
#pragma unroll
        for (int i = 0; i < 4; ++i) st[i] = (f32x4){0.f, 0.f, 0.f, 0.f};
        __builtin_amdgcn_s_setprio(1);
#pragma unroll
        for (int ki = 0; ki < 4; ++ki) {
            bf16x8 kf0 = *(const bf16x8*)(Ks + (ki * 16 + lr) * 72 + lg * 8);
            bf16x8 kf1 = *(const bf16x8*)(Ks + (ki * 16 + lr) * 72 + 32 + lg * 8);
            st[ki] = MFMA16(kf0, qf0, st[ki]);
            st[ki] = MFMA16(kf1, qf1, st[ki]);
        }
        __builtin_amdgcn_s_setprio(0);
        bool diag = (kt == qt);
        float pm = -1e30f;
#pragma unroll
        for (int ki = 0; ki < 4; ++ki) {
#pragma unroll
            for (int j = 0; j < 4; ++j) {
                float sv = st[ki][j] * 0.125f;
                if (diag) {
                    int gk = kt * 64 + ki * 16 + lg * 4 + j;
                    if (gk > gq) sv = -1e30f;
                }
                st[ki][j] = sv;
                pm = fmaxf(pm, sv);
            }
        }
        pm = fmaxf(pm, __shfl_xor(pm, 16));
        pm = fmaxf(pm, __shfl_xor(pm, 32));
        float m_new = fmaxf(m_run, pm);
        float alpha = __expf(m_run - m_new);
        float rs = 0.f;
#pragma unroll
        for (int ki = 0; ki < 4; ++ki) {
            bf16x4 pb;
#pragma unroll
            for (int j = 0; j < 4; ++j) {
                float pv = __expf(st[ki][j] - m_new);
                rs += pv;
                pb[j] = (bf16)pv;
            }
            *(bf16x4*)(Pw + lr * 72 + ki * 16 + lg * 4) = pb;
        }
        rs += __shfl_xor(rs, 16);
        rs += __shfl_xor(rs, 32);
        l_run = l_run * alpha + rs;
        m_run = m_new;
#pragma unroll
        for (int di = 0; di < 4; ++di) o[di] *= alpha;
        __builtin_amdgcn_s_setprio(1);
#pragma unroll
        for (int dk = 0; dk < 2; ++dk) {
            bf16x8 pf = *(const bf16x8*)(Pw + lr * 72 + dk * 32 + lg * 8);
#pragma unroll
            for (int di = 0; di < 4; ++di) {
                bf16x8 vf = *(const bf16x8*)(Vt + (di * 16 + lr) * 72 + dk * 32 + lg * 8);
                o[di] = MFMA16(vf, pf, o[di]);
            }
        }
        __builtin_amdgcn_s_setprio(0);
    }
    float inv = 1.0f / l_run;
    bf16* optr = AO + (size_t)qrow * 1024 + h * 64;
#pragma unroll
    for (int di = 0; di < 4; ++di) {
        bf16x4 ov;
#pragma unroll
        for (int j = 0; j < 4; ++j) ov[j] = (bf16)(o[di][j] * inv);
        *(bf16x4*)(optr + di * 16 + lg * 4) = ov;
    }
}

// ---------------- driver ----------------

extern "C" void kernel_launch(void* const* d_in, const int* in_sizes, int n_in,
                              void* d_out, int out_size, void* d_ws, size_t ws_size,
                              hipStream_t stream) {
    const int* tokens = (const int*)d_in[0];
    const float* embed_w = (const float*)d_in[1];
    const float* qkv_w = (const float*)d_in[2];
    const float* o_w = (const float*)d_in[3];
    const float* gate_w = (const float*)d_in[4];
    const float* up_w = (const float*)d_in[5];
    const float* down_w = (const float*)d_in[6];
    const float* norm1_w = (const float*)d_in[7];
    const float* norm2_w = (const float*)d_in[8];
    const float* scale_gamma = (const float*)d_in[9];
    const float* scale_beta = (const float*)d_in[10];
    const float* iter_scale = (const float*)d_in[11];
    const float* norm_w = (const float*)d_in[12];
    const float* lm_head_w = (const float*)d_in[13];

    char* p = (char*)d_ws;
    auto alloc = [&](size_t nbytes) -> char* {
        char* r = p;
        p += (nbytes + 255) & ~(size_t)255;
        return r;
    };
    bf16* WQKV = (bf16*)alloc(3072ull * 1024 * 2);
    bf16* WO   = (bf16*)alloc(1024ull * 1024 * 2);
    bf16* WG   = (bf16*)alloc(2048ull * 1024 * 2);
    bf16* WU   = (bf16*)alloc(2048ull * 1024 * 2);
    bf16* WD   = (bf16*)alloc(1024ull * 2048 * 2);
    bf16* WLM  = (bf16*)alloc(32000ull * 1024 * 2);
    float* X   = (float*)alloc(2048ull * 1024 * 4);
    float* X1  = (float*)alloc(2048ull * 1024 * 4);
    bf16* H    = (bf16*)alloc(2048ull * 1024 * 2);
    bf16* QKVb = (bf16*)alloc(2048ull * 3072 * 2);
    bf16* VT   = (bf16*)alloc(2048ull * 1024 * 2);
    bf16* AO   = (bf16*)alloc(2048ull * 1024 * 2);
    bf16* FF   = (bf16*)alloc(2048ull * 2048 * 2);

    cvt_kernel<<<1024, 256, 0, stream>>>(qkv_w, WQKV, 3072 * 1024 / 4);
    cvt_kernel<<<1024, 256, 0, stream>>>(o_w, WO, 1024 * 1024 / 4);
    cvt_kernel<<<1024, 256, 0, stream>>>(gate_w, WG, 2048 * 1024 / 4);
    cvt_kernel<<<1024, 256, 0, stream>>>(up_w, WU, 2048 * 1024 / 4);
    cvt_kernel<<<1024, 256, 0, stream>>>(down_w, WD, 1024 * 2048 / 4);
    cvt_kernel<<<2048, 256, 0, stream>>>(lm_head_w, WLM, 32000 * 1024 / 4);
    embed_kernel<<<2048, 256, 0, stream>>>(tokens, embed_w, X);

    for (int l = 0; l < 32; ++l) {
        const float* gm = scale_gamma + (size_t)(l >> 3) * 1024;
        const float* bt = scale_beta + (size_t)(l >> 3) * 1024;
        rmsnorm_kernel<true><<<2048, 256, 0, stream>>>(X, norm1_w, gm, bt, H);
        // QKV: B=6MB > A=4MB -> bm-fastest
        gemm_bt<4, 0, false><<<24 * 16, 256, 0, stream>>>(H, WQKV, 24, 16, 3072, 1024,
                                                          QKVb, nullptr, nullptr, nullptr, nullptr, nullptr);
        vtrans_kernel<<<dim3(16, 32), 256, 0, stream>>>(QKVb, VT);
        attn_kernel<<<dim3(16, 32), 256, 0, stream>>>(QKVb, VT, AO);
        // o-proj: A=4MB > B=2MB -> bn-fastest
        gemm_bt<2, 1, true><<<8 * 32, 256, 0, stream>>>(AO, WO, 8, 32, 1024, 1024,
                                                        nullptr, nullptr, X, nullptr, X1, nullptr);
        rmsnorm_kernel<true><<<2048, 256, 0, stream>>>(X1, norm2_w, gm, bt, H);
        gemm_gateup<<<256, 256, 0, stream>>>(H, WG, WU, FF);
        // down: A=8MB > B=4MB -> bn-fastest
        gemm_bt<2, 2, true><<<8 * 32, 256, 0, stream>>>(FF, WD, 8, 32, 1024, 2048,
                                                        nullptr, nullptr, X, X1, X, iter_scale + l);
    }
    rmsnorm_kernel<false><<<2048, 256, 0, stream>>>(X, norm_w, nullptr, nullptr, H);
    // lm_head: B=65MB >> A=4MB -> bm-fastest
    gemm_bt<4, 3, false><<<250 * 16, 256, 0, stream>>>(H, WLM, 250, 16, 32000, 1024,
                                                       nullptr, (float*)d_out, nullptr, nullptr, nullptr, nullptr);
}